// Round 1
// baseline (1494.544 us; speedup 1.0000x reference)
//
#include <hip/hip_runtime.h>
#include <math.h>

#define NXY  1024
#define NZ   24
#define ROI2 512      // 2*ROISize
#define LO_  256      // Nxy/2 - ROISize
#define EXT  64       // NxyExt
#define IMGW 896      // Nxy - 2*EXT
#define ITN  2
#define SNR_ 200.0f
#define BKG  110.0f
#define RANK1 524287u
#define RANK2 524288u

typedef float2 cf;

// ---------------- 1024-pt Stockham radix-2 FFT in LDS, 256 threads ----------------
__device__ __forceinline__ void twinit(cf* TW) {
  const float TWO_PI = 6.28318530717958647692f;
  for (int k = threadIdx.x; k < 512; k += 256) {
    float s, c;
    sincosf(-TWO_PI * (float)k / 1024.0f, &s, &c);
    TW[k] = make_float2(c, s);
  }
}

template <int SIGN>  // -1 forward, +1 inverse (unnormalized)
__device__ void fft1024(cf* X, cf* Y, const cf* TW) {
  int tid = threadIdx.x;
  cf* src = X;
  cf* dst = Y;
#pragma unroll
  for (int stage = 0; stage < 10; ++stage) {
    __syncthreads();
    const int s = 1 << stage;
    const int m = 1 << (9 - stage);
#pragma unroll
    for (int half = 0; half < 2; ++half) {
      int w = tid + half * 256;      // [0,512)
      int p = w >> stage;            // < m
      int q = w & (s - 1);
      cf a = src[q + s * p];
      cf b = src[q + s * (p + m)];
      cf tw = TW[p << stage];        // W_N^{p*N/n}
      float twy = (SIGN < 0) ? tw.y : -tw.y;
      cf sum = make_float2(a.x + b.x, a.y + b.y);
      cf dif = make_float2(a.x - b.x, a.y - b.y);
      cf t = make_float2(dif.x * tw.x - dif.y * twy, dif.x * twy + dif.y * tw.x);
      dst[q + s * (2 * p)]     = sum;
      dst[q + s * (2 * p) + s] = t;
    }
    cf* tmp = src; src = dst; dst = tmp;
  }
  __syncthreads();  // 10 stages (even) -> result back in X, natural order
}

// ---------------- setup kernels ----------------
__global__ void ksum_kernel(const float* __restrict__ a, float* __restrict__ out) {
  __shared__ float s[256];
  int tid = threadIdx.x;
  float acc = 0.f;
  for (int i = blockIdx.x * 256 + tid; i < NXY * NXY; i += gridDim.x * 256) acc += a[i];
  s[tid] = acc;
  __syncthreads();
  for (int o = 128; o > 0; o >>= 1) {
    if (tid < o) s[tid] += s[tid + o];
    __syncthreads();
  }
  if (tid == 0) atomicAdd(out, s[0]);
}

__global__ void imgexp_kernel(const float* __restrict__ im, float* __restrict__ out) {
  int idx = blockIdx.x * 256 + threadIdx.x;
  int r = idx >> 10, c = idx & 1023;
  float v = 0.f;
  if (r >= EXT && r < NXY - EXT && c >= EXT && c < NXY - EXT) {
    float t = im[(size_t)(r - EXT) * IMGW + (c - EXT)] - BKG;
    v = t > 0.f ? t : 0.f;
  }
  out[idx] = v;
}

// KT[c][r] = conv_re[r][c] + i*conv_im[r][c]   (tiled transpose)
__global__ void buildkt_kernel(const float* __restrict__ kre, const float* __restrict__ kim,
                               cf* __restrict__ kt) {
  __shared__ cf tile[32][33];
  int bc = blockIdx.x * 32, br = blockIdx.y * 32;
  int tx = threadIdx.x, ty = threadIdx.y;
#pragma unroll
  for (int j = 0; j < 32; j += 8) {
    int r = br + ty + j, c = bc + tx;
    tile[ty + j][tx] = make_float2(kre[(size_t)r * NXY + c], kim[(size_t)r * NXY + c]);
  }
  __syncthreads();
#pragma unroll
  for (int j = 0; j < 32; j += 8) {
    int c = bc + ty + j, r2 = br + tx;
    kt[(size_t)c * NXY + r2] = tile[tx][ty + j];
  }
}

// generic complex transpose [R][C] -> [C][R], batched over blockIdx.z
__global__ void transpose_kernel(const cf* __restrict__ in, cf* __restrict__ out, int R, int C) {
  __shared__ cf tile[32][33];
  size_t zoff = (size_t)blockIdx.z * R * C;
  const cf* src = in + zoff;
  cf* dst = out + zoff;
  int bc = blockIdx.x * 32, br = blockIdx.y * 32;
  int tx = threadIdx.x, ty = threadIdx.y;
#pragma unroll
  for (int j = 0; j < 32; j += 8) tile[ty + j][tx] = src[(size_t)(br + ty + j) * C + bc + tx];
  __syncthreads();
#pragma unroll
  for (int j = 0; j < 32; j += 8) dst[(size_t)(bc + ty + j) * R + br + tx] = tile[tx][ty + j];
}

// ---------------- FFT pipeline kernels ----------------
// Row FFT of a real input. grid = (rowsPerSlice, zchunk). in row length rowLen placed at [rowOff, rowOff+rowLen).
__global__ __launch_bounds__(256) void pass1_kernel(const float* __restrict__ in, int rowLen, int rowOff,
                                                    cf* __restrict__ out, int z0) {
  __shared__ cf X[1024], Y[1024], TW[512];
  int tid = threadIdx.x;
  int r = blockIdx.x;
  int zl = blockIdx.y;
  twinit(TW);
  const float* row = in + ((size_t)(z0 + zl) * gridDim.x + r) * rowLen;
  for (int k = tid; k < 1024; k += 256) {
    float v = 0.f;
    if (k >= rowOff && k < rowOff + rowLen) v = row[k - rowOff];
    X[k] = make_float2(v, 0.f);
  }
  fft1024<-1>(X, Y, TW);
  cf* dst = out + ((size_t)zl * gridDim.x + r) * NXY;
  for (int k = tid; k < 1024; k += 256) dst[k] = X[k];
}

// Column FFT (via transposed layout) * K (optionally conj) then column IFFT.
// in: [z][NXY][inLen], K column cached; out: [z][NXY][NXY]
__global__ __launch_bounds__(256) void pass2_kernel(const cf* __restrict__ in, int inLen, int inOff,
                                                    const cf* __restrict__ kt, cf* __restrict__ out,
                                                    int zn, int conjK) {
  __shared__ cf X[1024], Y[1024], TW[512], KL[1024];
  int tid = threadIdx.x;
  int kc = blockIdx.x;
  twinit(TW);
  const cf* krow = kt + (size_t)kc * NXY;
  for (int k = tid; k < 1024; k += 256) {
    cf v = krow[k];
    if (conjK) v.y = -v.y;
    KL[k] = v;
  }
  for (int z = 0; z < zn; ++z) {
    const cf* src = in + ((size_t)z * NXY + kc) * inLen;
    for (int k = tid; k < 1024; k += 256) {
      cf v = make_float2(0.f, 0.f);
      if (k >= inOff && k < inOff + inLen) v = src[k - inOff];
      X[k] = v;
    }
    fft1024<-1>(X, Y, TW);
    for (int k = tid; k < 1024; k += 256) {
      cf a = X[k], b = KL[k];
      X[k] = make_float2(a.x * b.x - a.y * b.y, a.x * b.y + a.y * b.x);
    }
    fft1024<1>(X, Y, TW);
    cf* dst = out + ((size_t)z * NXY + kc) * NXY;
    for (int k = tid; k < 1024; k += 256) dst[k] = X[k];
    __syncthreads();
  }
}

// Row IFFT + scale + ReLU + accumulate into ImgEst. grid = (NXY). Block owns row r exclusively.
__global__ __launch_bounds__(256) void pass3_fwd_kernel(const cf* __restrict__ in, float* __restrict__ imgest,
                                                        const float* __restrict__ ksump, int zn) {
  __shared__ cf X[1024], Y[1024], TW[512];
  int tid = threadIdx.x;
  int r = blockIdx.x;
  twinit(TW);
  float scale = 1.0f / (1048576.0f * ksump[0]);  // two unnormalized inverse FFTs -> 1024^2
  float a0 = 0.f, a1 = 0.f, a2 = 0.f, a3 = 0.f;
  for (int z = 0; z < zn; ++z) {
    const cf* src = in + ((size_t)z * NXY + r) * NXY;
    for (int k = tid; k < 1024; k += 256) X[k] = src[k];
    fft1024<1>(X, Y, TW);
    float v;
    v = X[tid].x * scale;       a0 += v > 0.f ? v : 0.f;
    v = X[tid + 256].x * scale; a1 += v > 0.f ? v : 0.f;
    v = X[tid + 512].x * scale; a2 += v > 0.f ? v : 0.f;
    v = X[tid + 768].x * scale; a3 += v > 0.f ? v : 0.f;
    __syncthreads();
  }
  float* dst = imgest + (size_t)r * NXY;
  dst[tid]       += a0;
  dst[tid + 256] += a1;
  dst[tid + 512] += a2;
  dst[tid + 768] += a3;
}

// Row IFFT of back-projection + ReLU + multiply into obj (all z). grid = (512) rows of the ROI.
__global__ __launch_bounds__(256) void pass3_back_kernel(const cf* __restrict__ in, float* __restrict__ obj,
                                                         const float* __restrict__ ksump) {
  __shared__ cf X[1024], Y[1024], TW[512];
  __shared__ float backrow[512];
  int tid = threadIdx.x;
  int rp = blockIdx.x;       // 0..511
  int r = rp + LO_;
  twinit(TW);
  float scale = 1.0f / (1048576.0f * ksump[0]);
  const cf* src = in + (size_t)r * NXY;
  for (int k = tid; k < 1024; k += 256) X[k] = src[k];
  fft1024<1>(X, Y, TW);
  for (int k = tid; k < 512; k += 256) {
    float v = X[k + LO_].x * scale;
    backrow[k] = v > 0.f ? v : 0.f;
  }
  __syncthreads();
  for (int idx = tid; idx < NZ * ROI2; idx += 256) {
    int z = idx >> 9;
    int c = idx & 511;
    size_t o = ((size_t)z * ROI2 + rp) * ROI2 + c;
    obj[o] *= backrow[c];
  }
}

// ---------------- median (dual radix-select on IEEE bits; ImgEst >= 0) ----------------
__global__ void medinit_kernel(unsigned* st) {
  if (threadIdx.x == 0) { st[0] = 0u; st[1] = 0u; st[2] = RANK1; st[3] = RANK2; }
}

__global__ void medhist_kernel(const float* __restrict__ v, const unsigned* __restrict__ st,
                               unsigned* __restrict__ hist, int shift) {
  __shared__ unsigned h[512];
  int tid = threadIdx.x;
  h[tid] = 0u; h[tid + 256] = 0u;
  __syncthreads();
  unsigned p1 = st[0], p2 = st[1];
  unsigned maskHigh = (shift >= 24) ? 0u : (0xFFFFFFFFu << (shift + 8));
  for (int i = blockIdx.x * 256 + tid; i < NXY * NXY; i += gridDim.x * 256) {
    unsigned u = __float_as_uint(v[i]);
    unsigned b = (u >> shift) & 255u;
    if ((u & maskHigh) == (p1 & maskHigh)) atomicAdd(&h[b], 1u);
    if ((u & maskHigh) == (p2 & maskHigh)) atomicAdd(&h[256 + b], 1u);
  }
  __syncthreads();
  atomicAdd(&hist[tid], h[tid]);
  atomicAdd(&hist[tid + 256], h[tid + 256]);
}

__global__ void medpick_kernel(unsigned* st, const unsigned* hist, int shift) {
  if (threadIdx.x == 0) {
    unsigned r1 = st[2], cum = 0u;
    for (int b = 0; b < 256; ++b) {
      unsigned c = hist[b];
      if (cum + c > r1) { st[0] |= ((unsigned)b) << shift; st[2] = r1 - cum; break; }
      cum += c;
    }
    unsigned r2 = st[3]; cum = 0u;
    for (int b = 0; b < 256; ++b) {
      unsigned c = hist[256 + b];
      if (cum + c > r2) { st[1] |= ((unsigned)b) << shift; st[3] = r2 - cum; break; }
      cum += c;
    }
  }
}

__global__ void medfinal_kernel(const unsigned* st, float* tos) {
  if (threadIdx.x == 0) {
    float m = 0.5f * (__uint_as_float(st[0]) + __uint_as_float(st[1]));
    tos[0] = m / SNR_;
  }
}

__global__ void ratio_kernel(const float* __restrict__ iexp, const float* __restrict__ iest,
                             const float* __restrict__ tos, float* __restrict__ ratio) {
  int idx = blockIdx.x * 256 + threadIdx.x;
  int r = idx >> 10, c = idx & 1023;
  float v = 1.0f;
  if (r >= EXT && r < NXY - EXT && c >= EXT && c < NXY - EXT)
    v = iexp[idx] / (iest[idx] + tos[0]);
  ratio[idx] = v;
}

// ---------------- orchestration ----------------
extern "C" void kernel_launch(void* const* d_in, const int* in_sizes, int n_in,
                              void* d_out, int out_size, void* d_ws, size_t ws_size,
                              hipStream_t stream) {
  const float* imstack  = (const float*)d_in[0];
  const float* init_vol = (const float*)d_in[1];
  const float* conv_re  = (const float*)d_in[2];
  const float* conv_im  = (const float*)d_in[3];
  float* obj = (float*)d_out;

  char* w = (char*)d_ws;
  size_t off = 0;
  auto alloc = [&](size_t bytes) -> void* {
    void* p = (void*)(w + off);
    off += (bytes + 255) & ~(size_t)255;
    return p;
  };

  cf* KT        = (cf*)alloc((size_t)NXY * NXY * sizeof(cf));  // 8 MB
  float* IExp   = (float*)alloc((size_t)NXY * NXY * 4);        // 4 MB
  float* IEst   = (float*)alloc((size_t)NXY * NXY * 4);        // 4 MB
  float* Ratio  = (float*)alloc((size_t)NXY * NXY * 4);        // 4 MB
  float* Ksum   = (float*)alloc(256);                          // [0]=ksum, [1]=tmp/SNR
  unsigned* St  = (unsigned*)alloc(256);                       // 4 state words
  unsigned* Hist= (unsigned*)alloc(2048);                      // 2x256 bins
  size_t fixedEnd = off;

  int ZC = 1;
  const int zcs[4] = {8, 4, 2, 1};
  for (int i = 0; i < 4; ++i) {
    size_t need = fixedEnd + (size_t)zcs[i] * 24ull * 1024 * 1024 + 4096;
    if (need <= ws_size) { ZC = zcs[i]; break; }
  }
  cf* bufA = (cf*)alloc((size_t)ZC * 512 * NXY * sizeof(cf));  // row-FFT out  [z][512][1024]
  cf* bufB = (cf*)alloc((size_t)ZC * 512 * NXY * sizeof(cf));  // transposed   [z][1024][512]
  cf* bufC = (cf*)alloc((size_t)ZC * NXY * NXY * sizeof(cf));  // col pipeline [z][1024][1024]
  cf* bufD = (cf*)alloc((size_t)ZC * NXY * NXY * sizeof(cf));

  float* Tos = Ksum + 1;

  // obj <- init_vol ; Ksum ; ImgExp ; KT
  hipMemcpyAsync(obj, init_vol, (size_t)NZ * ROI2 * ROI2 * 4, hipMemcpyDeviceToDevice, stream);
  hipMemsetAsync(Ksum, 0, 8, stream);
  ksum_kernel<<<256, 256, 0, stream>>>(conv_re, Ksum);
  imgexp_kernel<<<4096, 256, 0, stream>>>(imstack, IExp);
  buildkt_kernel<<<dim3(32, 32), dim3(32, 8), 0, stream>>>(conv_re, conv_im, KT);

  for (int it = 0; it < ITN; ++it) {
    hipMemsetAsync(IEst, 0, (size_t)NXY * NXY * 4, stream);
    // forward projection in z-chunks
    for (int z0 = 0; z0 < NZ; z0 += ZC) {
      int zn = (NZ - z0 < ZC) ? (NZ - z0) : ZC;
      pass1_kernel<<<dim3(512, zn), 256, 0, stream>>>(obj, ROI2, LO_, bufA, z0);
      transpose_kernel<<<dim3(32, 16, zn), dim3(32, 8), 0, stream>>>(bufA, bufB, 512, 1024);
      pass2_kernel<<<1024, 256, 0, stream>>>(bufB, 512, LO_, KT, bufC, zn, 0);
      transpose_kernel<<<dim3(32, 32, zn), dim3(32, 8), 0, stream>>>(bufC, bufD, 1024, 1024);
      pass3_fwd_kernel<<<1024, 256, 0, stream>>>(bufD, IEst, Ksum, zn);
    }
    // median of ImgEst (exact, dual radix-select)
    medinit_kernel<<<1, 64, 0, stream>>>(St);
    for (int round = 0; round < 4; ++round) {
      int shift = 24 - 8 * round;
      hipMemsetAsync(Hist, 0, 2048, stream);
      medhist_kernel<<<512, 256, 0, stream>>>(IEst, St, Hist, shift);
      medpick_kernel<<<1, 64, 0, stream>>>(St, Hist, shift);
    }
    medfinal_kernel<<<1, 64, 0, stream>>>(St, Tos);
    ratio_kernel<<<4096, 256, 0, stream>>>(IExp, IEst, Tos, Ratio);
    // back projection (single plane)
    pass1_kernel<<<dim3(1024, 1), 256, 0, stream>>>(Ratio, NXY, 0, bufC, 0);
    transpose_kernel<<<dim3(32, 32, 1), dim3(32, 8), 0, stream>>>(bufC, bufD, 1024, 1024);
    pass2_kernel<<<1024, 256, 0, stream>>>(bufD, NXY, 0, KT, bufC, 1, 1);
    transpose_kernel<<<dim3(32, 32, 1), dim3(32, 8), 0, stream>>>(bufC, bufD, 1024, 1024);
    pass3_back_kernel<<<512, 256, 0, stream>>>(bufD, obj, Ksum);
  }
}

// Round 3
// 1025.652 us; speedup vs baseline: 1.4572x; 1.4572x over previous
//
#include <hip/hip_runtime.h>
#include <math.h>

#define NXY  1024
#define NZ   24
#define ROI2 512      // 2*ROISize
#define LO_  256      // Nxy/2 - ROISize
#define EXT  64       // NxyExt
#define IMGW 896      // Nxy - 2*EXT
#define ITN  2
#define SNR_ 200.0f
#define BKG  110.0f
#define RANK1 524287u
#define RANK2 524288u
#define NACC 8        // parallel accumulator planes for pass3 forward

typedef float2 cf;

__device__ __forceinline__ cf cadd(cf a, cf b) { return make_float2(a.x + b.x, a.y + b.y); }
__device__ __forceinline__ cf csub(cf a, cf b) { return make_float2(a.x - b.x, a.y - b.y); }
__device__ __forceinline__ cf cmul(cf a, cf b) { return make_float2(a.x * b.x - a.y * b.y, a.x * b.y + a.y * b.x); }

// TW[k] = exp(-2*pi*i*k/1024), k in [0,256)
__device__ __forceinline__ void twinit(cf* TW) {
  int k = threadIdx.x;  // blockDim == 256
  float s, c;
  sincosf(-6.28318530717958647692f * (float)k / 1024.0f, &s, &c);
  TW[k] = make_float2(c, s);
}

// 1024-pt radix-4 Stockham DIF, 256 threads, 5 stages. Returns buffer holding result
// (natural order). SIGN=-1 forward, +1 inverse (unnormalized).
template <int SIGN>
__device__ cf* fft1024_r4(cf* src, cf* dst, const cf* TW) {
  const int tid = threadIdx.x;
#pragma unroll
  for (int t = 0; t < 5; ++t) {
    __syncthreads();
    const int s = 1 << (2 * t);
    const int q = tid & (s - 1);
    const int sp = tid - q;            // s*p, < 256
    cf a0 = src[tid];
    cf a1 = src[tid + 256];
    cf a2 = src[tid + 512];
    cf a3 = src[tid + 768];
    cf b0 = cadd(a0, a2), b1 = csub(a0, a2);
    cf b2 = cadd(a1, a3), b3 = csub(a1, a3);
    cf jb3 = (SIGN < 0) ? make_float2(b3.y, -b3.x) : make_float2(-b3.y, b3.x);
    cf c0 = cadd(b0, b2);
    cf c2 = csub(b0, b2);
    cf c1 = cadd(b1, jb3);
    cf c3 = csub(b1, jb3);
    cf t1 = TW[sp];
    if (SIGN > 0) t1.y = -t1.y;
    cf t2 = cmul(t1, t1);
    cf t3 = cmul(t2, t1);
    const int base = 4 * tid - 3 * q;  // q + s*4p
    dst[base]         = c0;
    dst[base + s]     = cmul(c1, t1);
    dst[base + 2 * s] = cmul(c2, t2);
    dst[base + 3 * s] = cmul(c3, t3);
    cf* tmp = src; src = dst; dst = tmp;
  }
  __syncthreads();
  return src;
}

// ---------------- setup kernels ----------------
__global__ void ksum_kernel(const float* __restrict__ a, float* __restrict__ out) {
  __shared__ float s[256];
  int tid = threadIdx.x;
  float acc = 0.f;
  for (int i = blockIdx.x * 256 + tid; i < NXY * NXY; i += gridDim.x * 256) acc += a[i];
  s[tid] = acc;
  __syncthreads();
  for (int o = 128; o > 0; o >>= 1) {
    if (tid < o) s[tid] += s[tid + o];
    __syncthreads();
  }
  if (tid == 0) atomicAdd(out, s[0]);
}

__global__ void imgexp_kernel(const float* __restrict__ im, float* __restrict__ out) {
  int idx = blockIdx.x * 256 + threadIdx.x;
  int r = idx >> 10, c = idx & 1023;
  float v = 0.f;
  if (r >= EXT && r < NXY - EXT && c >= EXT && c < NXY - EXT) {
    float t = im[(size_t)(r - EXT) * IMGW + (c - EXT)] - BKG;
    v = t > 0.f ? t : 0.f;
  }
  out[idx] = v;
}

// KT[c][r] = conv_re[r][c] + i*conv_im[r][c]
__global__ void buildkt_kernel(const float* __restrict__ kre, const float* __restrict__ kim,
                               cf* __restrict__ kt) {
  __shared__ cf tile[32][33];
  int bc = blockIdx.x * 32, br = blockIdx.y * 32;
  int tx = threadIdx.x, ty = threadIdx.y;
#pragma unroll
  for (int j = 0; j < 32; j += 8) {
    int r = br + ty + j, c = bc + tx;
    tile[ty + j][tx] = make_float2(kre[(size_t)r * NXY + c], kim[(size_t)r * NXY + c]);
  }
  __syncthreads();
#pragma unroll
  for (int j = 0; j < 32; j += 8) {
    int c = bc + ty + j, r2 = br + tx;
    kt[(size_t)c * NXY + r2] = tile[tx][ty + j];
  }
}

// complex transpose [R][C] -> [C][R], batched over blockIdx.z
__global__ void transpose_kernel(const cf* __restrict__ in, cf* __restrict__ out, int R, int C) {
  __shared__ cf tile[32][33];
  size_t zoff = (size_t)blockIdx.z * R * C;
  const cf* src = in + zoff;
  cf* dst = out + zoff;
  int bc = blockIdx.x * 32, br = blockIdx.y * 32;
  int tx = threadIdx.x, ty = threadIdx.y;
#pragma unroll
  for (int j = 0; j < 32; j += 8) tile[ty + j][tx] = src[(size_t)(br + ty + j) * C + bc + tx];
  __syncthreads();
#pragma unroll
  for (int j = 0; j < 32; j += 8) dst[(size_t)(bc + ty + j) * R + br + tx] = tile[tx][ty + j];
}

// ---------------- FFT pipeline kernels ----------------
// Row FFT of a real input. grid = (rowsPerSlice, zchunk).
__global__ __launch_bounds__(256) void pass1_kernel(const float* __restrict__ in, int rowLen, int rowOff,
                                                    cf* __restrict__ out, int z0) {
  __shared__ cf X[1024], Y[1024], TW[256];
  int tid = threadIdx.x;
  int r = blockIdx.x;
  int zl = blockIdx.y;
  twinit(TW);
  const float* row = in + ((size_t)(z0 + zl) * gridDim.x + r) * rowLen;
  for (int k = tid; k < 1024; k += 256) {
    float v = 0.f;
    if (k >= rowOff && k < rowOff + rowLen) v = row[k - rowOff];
    X[k] = make_float2(v, 0.f);
  }
  cf* G = fft1024_r4<-1>(X, Y, TW);
  cf* dst = out + ((size_t)zl * gridDim.x + r) * NXY;
  for (int k = tid; k < 1024; k += 256) dst[k] = G[k];
}

// Back-projection row FFT with ratio computation fused in. grid = (1024).
__global__ __launch_bounds__(256) void pass1b_kernel(const float* __restrict__ iexp,
                                                     const float* __restrict__ iest,
                                                     const float* __restrict__ tos,
                                                     cf* __restrict__ out) {
  __shared__ cf X[1024], Y[1024], TW[256];
  int tid = threadIdx.x;
  int r = blockIdx.x;
  twinit(TW);
  float t = tos[0];
  bool rin = (r >= EXT && r < NXY - EXT);
  for (int k = tid; k < 1024; k += 256) {
    float v = 1.0f;
    if (rin && k >= EXT && k < NXY - EXT)
      v = iexp[(size_t)r * NXY + k] / (iest[(size_t)r * NXY + k] + t);
    X[k] = make_float2(v, 0.f);
  }
  cf* G = fft1024_r4<-1>(X, Y, TW);
  cf* dst = out + (size_t)r * NXY;
  for (int k = tid; k < 1024; k += 256) dst[k] = G[k];
}

// Column FFT * K (optionally conj) then column IFFT, z-parallel with small z-loop.
// in: [z][NXY][inLen]; out: [z][NXY][NXY]. grid = (1024, ceil(zn/ZB)).
__global__ __launch_bounds__(256) void pass2_kernel(const cf* __restrict__ in, int inLen, int inOff,
                                                    const cf* __restrict__ kt, cf* __restrict__ out,
                                                    int zn, int ZB, int conjK) {
  __shared__ cf X[1024], Y[1024], TW[256], KL[1024];
  int tid = threadIdx.x;
  int kc = blockIdx.x;
  twinit(TW);
  const cf* krow = kt + (size_t)kc * NXY;
  for (int k = tid; k < 1024; k += 256) {
    cf v = krow[k];
    if (conjK) v.y = -v.y;
    KL[k] = v;
  }
  int zlo = blockIdx.y * ZB;
  int zhi = min(zn, zlo + ZB);
  for (int z = zlo; z < zhi; ++z) {
    const cf* src = in + ((size_t)z * NXY + kc) * inLen;
    for (int k = tid; k < 1024; k += 256) {
      cf v = make_float2(0.f, 0.f);
      if (k >= inOff && k < inOff + inLen) v = src[k - inOff];
      X[k] = v;
    }
    cf* F = fft1024_r4<-1>(X, Y, TW);          // F == Y
    for (int k = tid; k < 1024; k += 256) F[k] = cmul(F[k], KL[k]);
    cf* G = fft1024_r4<1>(F, (F == X) ? Y : X, TW);
    cf* dst = out + ((size_t)z * NXY + kc) * NXY;
    for (int k = tid; k < 1024; k += 256) dst[k] = G[k];
    __syncthreads();
  }
}

// Row IFFT + scale + ReLU, accumulate into partial plane `a`. grid = (1024, NACC).
__global__ __launch_bounds__(256) void pass3_fwd_kernel(const cf* __restrict__ in,
                                                        float* __restrict__ partials,
                                                        const float* __restrict__ ksump, int zn) {
  __shared__ cf X[1024], Y[1024], TW[256];
  int tid = threadIdx.x;
  int r = blockIdx.x;
  int a = blockIdx.y;
  twinit(TW);
  float scale = 1.0f / (1048576.0f * ksump[0]);
  float acc0 = 0.f, acc1 = 0.f, acc2 = 0.f, acc3 = 0.f;
  for (int z = a; z < zn; z += NACC) {
    const cf* src = in + ((size_t)z * NXY + r) * NXY;
    for (int k = tid; k < 1024; k += 256) X[k] = src[k];
    cf* G = fft1024_r4<1>(X, Y, TW);
    float v;
    v = G[tid].x * scale;       acc0 += v > 0.f ? v : 0.f;
    v = G[tid + 256].x * scale; acc1 += v > 0.f ? v : 0.f;
    v = G[tid + 512].x * scale; acc2 += v > 0.f ? v : 0.f;
    v = G[tid + 768].x * scale; acc3 += v > 0.f ? v : 0.f;
    __syncthreads();
  }
  float* dst = partials + ((size_t)a * NXY + r) * NXY;
  dst[tid]       += acc0;
  dst[tid + 256] += acc1;
  dst[tid + 512] += acc2;
  dst[tid + 768] += acc3;
}

__global__ void fold_kernel(const float* __restrict__ partials, float* __restrict__ iest) {
  int i = blockIdx.x * 256 + threadIdx.x;
  float s = 0.f;
#pragma unroll
  for (int a = 0; a < NACC; ++a) s += partials[(size_t)a * NXY * NXY + i];
  iest[i] = s;
}

// Back-projection row IFFT + ReLU + multiply into obj. grid = (512).
__global__ __launch_bounds__(256) void pass3_back_kernel(const cf* __restrict__ in, float* __restrict__ obj,
                                                         const float* __restrict__ ksump) {
  __shared__ cf X[1024], Y[1024], TW[256];
  __shared__ float backrow[512];
  int tid = threadIdx.x;
  int rp = blockIdx.x;
  int r = rp + LO_;
  twinit(TW);
  float scale = 1.0f / (1048576.0f * ksump[0]);
  const cf* src = in + (size_t)r * NXY;
  for (int k = tid; k < 1024; k += 256) X[k] = src[k];
  cf* G = fft1024_r4<1>(X, Y, TW);
  for (int k = tid; k < 512; k += 256) {
    float v = G[k + LO_].x * scale;
    backrow[k] = v > 0.f ? v : 0.f;
  }
  __syncthreads();
  for (int idx = tid; idx < NZ * ROI2; idx += 256) {
    int z = idx >> 9;
    int c = idx & 511;
    size_t o = ((size_t)z * ROI2 + rp) * ROI2 + c;
    obj[o] *= backrow[c];
  }
}

// ---------------- median (exact, 3-round radix-select: 11/11/10 bits) ----------------
__global__ void medinit_kernel(unsigned* st) {
  if (threadIdx.x == 0) { st[0] = 0u; st[1] = 0u; st[2] = RANK1; st[3] = RANK2; }
}

__global__ void medhist_kernel(const float* __restrict__ v, const unsigned* __restrict__ st,
                               unsigned* __restrict__ hist, int shift, unsigned maskHigh, int nb) {
  extern __shared__ unsigned h[];  // 2*nb
  int tid = threadIdx.x;
  for (int k = tid; k < 2 * nb; k += 256) h[k] = 0u;
  __syncthreads();
  unsigned p1 = st[0], p2 = st[1];
  unsigned bm = (unsigned)(nb - 1);
  for (int i = blockIdx.x * 256 + tid; i < NXY * NXY; i += gridDim.x * 256) {
    unsigned u = __float_as_uint(v[i]);
    unsigned b = (u >> shift) & bm;
    if ((u & maskHigh) == (p1 & maskHigh)) atomicAdd(&h[b], 1u);
    if ((u & maskHigh) == (p2 & maskHigh)) atomicAdd(&h[nb + b], 1u);
  }
  __syncthreads();
  for (int k = tid; k < 2 * nb; k += 256) atomicAdd(&hist[k], h[k]);
}

// Block-parallel pick over nb bins (nb/256 per thread), both pivots. 1 block x 256.
__global__ void medpick_kernel(unsigned* st, const unsigned* __restrict__ hist, int shift, int nb,
                               int finalRound, float* tos) {
  __shared__ unsigned ps[256];
  int t = threadIdx.x;
  int per = nb >> 8;  // nb/256 (<= 8)
  for (int which = 0; which < 2; ++which) {
    unsigned loc[8];
    unsigned my = 0;
    for (int i = 0; i < per; ++i) { loc[i] = hist[which * nb + t * per + i]; my += loc[i]; }
    ps[t] = my;
    __syncthreads();
    for (int off = 1; off < 256; off <<= 1) {
      unsigned v = (t >= off) ? ps[t - off] : 0u;
      __syncthreads();
      ps[t] += v;
      __syncthreads();
    }
    unsigned pre = ps[t] - my;
    unsigned r = st[2 + which];
    if (r >= pre && r < pre + my) {
      unsigned cum = pre;
      for (int i = 0; i < per; ++i) {
        if (r < cum + loc[i]) {
          st[which] |= (unsigned)(t * per + i) << shift;
          st[2 + which] = r - cum;
          break;
        }
        cum += loc[i];
      }
    }
    __syncthreads();
  }
  if (finalRound && t == 0) {
    float m = 0.5f * (__uint_as_float(st[0]) + __uint_as_float(st[1]));
    tos[0] = m / SNR_;
  }
}

// ---------------- orchestration ----------------
extern "C" void kernel_launch(void* const* d_in, const int* in_sizes, int n_in,
                              void* d_out, int out_size, void* d_ws, size_t ws_size,
                              hipStream_t stream) {
  const float* imstack  = (const float*)d_in[0];
  const float* init_vol = (const float*)d_in[1];
  const float* conv_re  = (const float*)d_in[2];
  const float* conv_im  = (const float*)d_in[3];
  float* obj = (float*)d_out;

  char* w = (char*)d_ws;
  size_t off = 0;
  auto alloc = [&](size_t bytes) -> void* {
    void* p = (void*)(w + off);
    off += (bytes + 255) & ~(size_t)255;
    return p;
  };

  const size_t PLANE = (size_t)NXY * NXY;
  cf* KT         = (cf*)alloc(PLANE * sizeof(cf));            // 8 MB
  float* IExp    = (float*)alloc(PLANE * 4);                  // 4 MB
  float* IEst    = (float*)alloc(PLANE * 4);                  // 4 MB
  float* Partial = (float*)alloc((size_t)NACC * PLANE * 4);   // 32 MB
  float* Ksum    = (float*)alloc(256);
  unsigned* St   = (unsigned*)alloc(256);
  unsigned* Hist = (unsigned*)alloc(2 * 2048 * 4);
  size_t fixedEnd = off;

  int ZC = 1;
  const int zcs[8] = {24, 12, 8, 6, 4, 3, 2, 1};
  for (int i = 0; i < 8; ++i) {
    size_t need = fixedEnd + (size_t)zcs[i] * 2ull * PLANE * sizeof(cf) + 4096;
    if (need <= ws_size) { ZC = zcs[i]; break; }
  }
  cf* bufC = (cf*)alloc((size_t)ZC * PLANE * sizeof(cf));
  cf* bufD = (cf*)alloc((size_t)ZC * PLANE * sizeof(cf));
  float* Tos = Ksum + 1;

  hipMemcpyAsync(obj, init_vol, (size_t)NZ * ROI2 * ROI2 * 4, hipMemcpyDeviceToDevice, stream);
  hipMemsetAsync(Ksum, 0, 8, stream);
  ksum_kernel<<<256, 256, 0, stream>>>(conv_re, Ksum);
  imgexp_kernel<<<4096, 256, 0, stream>>>(imstack, IExp);
  buildkt_kernel<<<dim3(32, 32), dim3(32, 8), 0, stream>>>(conv_re, conv_im, KT);

  const int shifts[3] = {21, 10, 0};
  const int nbs[3]    = {2048, 2048, 1024};
  const unsigned masks[3] = {0u, 0xFFE00000u, 0xFFFFFC00u};

  for (int it = 0; it < ITN; ++it) {
    hipMemsetAsync(Partial, 0, (size_t)NACC * PLANE * 4, stream);
    // forward projection in z-chunks
    for (int z0 = 0; z0 < NZ; z0 += ZC) {
      int zn = (NZ - z0 < ZC) ? (NZ - z0) : ZC;
      int nzb = (zn + 3) / 4;
      pass1_kernel<<<dim3(512, zn), 256, 0, stream>>>(obj, ROI2, LO_, bufC, z0);
      transpose_kernel<<<dim3(32, 16, zn), dim3(32, 8), 0, stream>>>(bufC, bufD, 512, 1024);
      pass2_kernel<<<dim3(1024, nzb), 256, 0, stream>>>(bufD, 512, LO_, KT, bufC, zn, 4, 0);
      transpose_kernel<<<dim3(32, 32, zn), dim3(32, 8), 0, stream>>>(bufC, bufD, 1024, 1024);
      pass3_fwd_kernel<<<dim3(1024, NACC), 256, 0, stream>>>(bufD, Partial, Ksum, zn);
    }
    fold_kernel<<<4096, 256, 0, stream>>>(Partial, IEst);
    // exact median of IEst
    medinit_kernel<<<1, 64, 0, stream>>>(St);
    for (int round = 0; round < 3; ++round) {
      hipMemsetAsync(Hist, 0, 2 * 2048 * 4, stream);
      medhist_kernel<<<256, 256, 2 * nbs[round] * 4, stream>>>(IEst, St, Hist, shifts[round],
                                                               masks[round], nbs[round]);
      medpick_kernel<<<1, 256, 0, stream>>>(St, Hist, shifts[round], nbs[round],
                                            round == 2 ? 1 : 0, Tos);
    }
    // back projection (ratio fused into row FFT)
    pass1b_kernel<<<1024, 256, 0, stream>>>(IExp, IEst, Tos, bufC);
    transpose_kernel<<<dim3(32, 32, 1), dim3(32, 8), 0, stream>>>(bufC, bufD, 1024, 1024);
    pass2_kernel<<<dim3(1024, 1), 256, 0, stream>>>(bufD, 1024, 0, KT, bufC, 1, 1, 1);
    transpose_kernel<<<dim3(32, 32, 1), dim3(32, 8), 0, stream>>>(bufC, bufD, 1024, 1024);
    pass3_back_kernel<<<512, 256, 0, stream>>>(bufD, obj, Ksum);
  }
}

// Round 4
// 705.854 us; speedup vs baseline: 2.1174x; 1.4531x over previous
//
#include <hip/hip_runtime.h>
#include <math.h>

#define NXY  1024
#define NZ   24
#define ROI2 512      // 2*ROISize
#define LO_  256      // Nxy/2 - ROISize
#define EXT  64       // NxyExt
#define IMGW 896      // Nxy - 2*EXT
#define ITN  2
#define SNR_ 200.0f
#define BKG  110.0f
#define RANK1 524287u
#define RANK2 524288u
#define NACC 8        // parallel accumulator planes for pass3 forward
#define PAD(i) ((i) + ((i) >> 4))   // LDS anti-bank-conflict padding (max idx 1023 -> 1086)

typedef float2 cf;

__device__ __forceinline__ cf cadd(cf a, cf b) { return make_float2(a.x + b.x, a.y + b.y); }
__device__ __forceinline__ cf csub(cf a, cf b) { return make_float2(a.x - b.x, a.y - b.y); }
__device__ __forceinline__ cf cmul(cf a, cf b) { return make_float2(a.x * b.x - a.y * b.y, a.x * b.y + a.y * b.x); }

// TW[k] = exp(-2*pi*i*k/1024), k in [0,256)
__device__ __forceinline__ void twinit(cf* TW) {
  int k = threadIdx.x;  // blockDim == 256
  float s, c;
  sincosf(-6.28318530717958647692f * (float)k / 1024.0f, &s, &c);
  TW[k] = make_float2(c, s);
}

// 1024-pt radix-4 Stockham DIF, 256 threads, 5 stages, padded LDS indexing.
// Returns buffer holding result (natural order). SIGN=-1 fwd, +1 inverse (unnormalized).
// 5 swaps: fft(X,Y) returns Y.
template <int SIGN>
__device__ cf* fft1024_r4(cf* src, cf* dst, const cf* TW) {
  const int tid = threadIdx.x;
#pragma unroll
  for (int t = 0; t < 5; ++t) {
    __syncthreads();
    const int s = 1 << (2 * t);
    const int q = tid & (s - 1);
    const int sp = tid - q;            // s*p, < 256
    cf a0 = src[PAD(tid)];
    cf a1 = src[PAD(tid + 256)];
    cf a2 = src[PAD(tid + 512)];
    cf a3 = src[PAD(tid + 768)];
    cf b0 = cadd(a0, a2), b1 = csub(a0, a2);
    cf b2 = cadd(a1, a3), b3 = csub(a1, a3);
    cf jb3 = (SIGN < 0) ? make_float2(b3.y, -b3.x) : make_float2(-b3.y, b3.x);
    cf c0 = cadd(b0, b2);
    cf c2 = csub(b0, b2);
    cf c1 = cadd(b1, jb3);
    cf c3 = csub(b1, jb3);
    cf t1v = TW[sp];
    if (SIGN > 0) t1v.y = -t1v.y;
    cf t2v = cmul(t1v, t1v);
    cf t3v = cmul(t2v, t1v);
    const int base = 4 * tid - 3 * q;  // q + s*4p
    dst[PAD(base)]         = c0;
    dst[PAD(base + s)]     = cmul(c1, t1v);
    dst[PAD(base + 2 * s)] = cmul(c2, t2v);
    dst[PAD(base + 3 * s)] = cmul(c3, t3v);
    cf* tmp = src; src = dst; dst = tmp;
  }
  __syncthreads();
  return src;
}

// ---------------- setup kernels ----------------
__global__ void ksum_kernel(const float* __restrict__ a, float* __restrict__ out) {
  __shared__ float s[256];
  int tid = threadIdx.x;
  float acc = 0.f;
  for (int i = blockIdx.x * 256 + tid; i < NXY * NXY; i += gridDim.x * 256) acc += a[i];
  s[tid] = acc;
  __syncthreads();
  for (int o = 128; o > 0; o >>= 1) {
    if (tid < o) s[tid] += s[tid + o];
    __syncthreads();
  }
  if (tid == 0) atomicAdd(out, s[0]);
}

__global__ void imgexp_kernel(const float* __restrict__ im, float* __restrict__ out) {
  int idx = blockIdx.x * 256 + threadIdx.x;
  int r = idx >> 10, c = idx & 1023;
  float v = 0.f;
  if (r >= EXT && r < NXY - EXT && c >= EXT && c < NXY - EXT) {
    float t = im[(size_t)(r - EXT) * IMGW + (c - EXT)] - BKG;
    v = t > 0.f ? t : 0.f;
  }
  out[idx] = v;
}

// KH_T[kx][ky] = Hermitian part of K, transposed: 0.5*(K[ky][kx] + conj(K[-ky][-kx]))
// kx in [0,512], ky in [0,1024). Re(ifft2(F*K)) == ifft2(F*K_H) for real-input F.
__global__ void buildkh_kernel(const float* __restrict__ kre, const float* __restrict__ kim,
                               cf* __restrict__ kt) {
  int idx = blockIdx.x * 256 + threadIdx.x;
  if (idx >= 513 * 1024) return;
  int ky = idx & 1023, kx = idx >> 10;
  int ny = (1024 - ky) & 1023, nx = (1024 - kx) & 1023;
  float ar = kre[(size_t)ky * NXY + kx], ai = kim[(size_t)ky * NXY + kx];
  float br = kre[(size_t)ny * NXY + nx], bi = kim[(size_t)ny * NXY + nx];
  kt[idx] = make_float2(0.5f * (ar + br), 0.5f * (ai - bi));
}

// complex transpose [R][C] -> [C][R], batched over blockIdx.z; grid (C/32, R/32, z)
__global__ void transpose_kernel(const cf* __restrict__ in, cf* __restrict__ out, int R, int C) {
  __shared__ cf tile[32][33];
  size_t zoff = (size_t)blockIdx.z * R * C;
  const cf* src = in + zoff;
  cf* dst = out + zoff;
  int bc = blockIdx.x * 32, br = blockIdx.y * 32;
  int tx = threadIdx.x, ty = threadIdx.y;
#pragma unroll
  for (int j = 0; j < 32; j += 8) tile[ty + j][tx] = src[(size_t)(br + ty + j) * C + bc + tx];
  __syncthreads();
#pragma unroll
  for (int j = 0; j < 32; j += 8) dst[(size_t)(bc + ty + j) * R + br + tx] = tile[tx][ty + j];
}

// ---------------- FFT pipeline kernels ----------------
// Row rFFT of TWO real rows packed as one complex FFT. grid = (npairs, zn).
// in: [z][2*npairs][rowLen] real; out: [z][2*npairs][512] cf half-spectra,
// col 0 packs (F[0], F[512]) (both real).
__global__ __launch_bounds__(256) void pass1_kernel(const float* __restrict__ in, int rowLen, int rowOff,
                                                    cf* __restrict__ out) {
  __shared__ cf X[1088], Y[1088], TW[256];
  int tid = threadIdx.x;
  int b = blockIdx.x, zl = blockIdx.y;
  int nrows = 2 * gridDim.x;
  twinit(TW);
  const float* r0 = in + ((size_t)zl * nrows + 2 * b) * rowLen;
  const float* r1 = r0 + rowLen;
  for (int k = tid; k < 1024; k += 256) {
    cf v = make_float2(0.f, 0.f);
    if (k >= rowOff && k < rowOff + rowLen) { v.x = r0[k - rowOff]; v.y = r1[k - rowOff]; }
    X[PAD(k)] = v;
  }
  cf* G = fft1024_r4<-1>(X, Y, TW);
  cf* o0 = out + ((size_t)zl * nrows + 2 * b) * 512;
  cf* o1 = o0 + 512;
  for (int k = tid; k < 512; k += 256) {
    if (k == 0) {
      cf g0 = G[PAD(0)], gn = G[PAD(512)];
      o0[0] = make_float2(g0.x, gn.x);
      o1[0] = make_float2(g0.y, gn.y);
    } else {
      cf c = G[PAD(k)], d = G[PAD(1024 - k)];
      o0[k] = make_float2(0.5f * (c.x + d.x), 0.5f * (c.y - d.y));
      o1[k] = make_float2(0.5f * (c.y + d.y), 0.5f * (d.x - c.x));
    }
  }
}

// Back-projection row rFFT with ratio fused. grid = (512). rows (2b, 2b+1); out [1024][512].
__global__ __launch_bounds__(256) void pass1b_kernel(const float* __restrict__ iexp,
                                                     const float* __restrict__ iest,
                                                     const float* __restrict__ tos,
                                                     cf* __restrict__ out) {
  __shared__ cf X[1088], Y[1088], TW[256];
  int tid = threadIdx.x, b = blockIdx.x;
  twinit(TW);
  float t = tos[0];
  int r0 = 2 * b, r1 = 2 * b + 1;
  bool in0 = (r0 >= EXT && r0 < NXY - EXT);
  bool in1 = (r1 >= EXT && r1 < NXY - EXT);
  for (int k = tid; k < 1024; k += 256) {
    bool kin = (k >= EXT && k < NXY - EXT);
    float v0 = (in0 && kin) ? iexp[(size_t)r0 * NXY + k] / (iest[(size_t)r0 * NXY + k] + t) : 1.0f;
    float v1 = (in1 && kin) ? iexp[(size_t)r1 * NXY + k] / (iest[(size_t)r1 * NXY + k] + t) : 1.0f;
    X[PAD(k)] = make_float2(v0, v1);
  }
  cf* G = fft1024_r4<-1>(X, Y, TW);
  cf* o0 = out + (size_t)r0 * 512;
  cf* o1 = out + (size_t)r1 * 512;
  for (int k = tid; k < 512; k += 256) {
    if (k == 0) {
      cf g0 = G[PAD(0)], gn = G[PAD(512)];
      o0[0] = make_float2(g0.x, gn.x);
      o1[0] = make_float2(g0.y, gn.y);
    } else {
      cf c = G[PAD(k)], d = G[PAD(1024 - k)];
      o0[k] = make_float2(0.5f * (c.x + d.x), 0.5f * (c.y - d.y));
      o1[k] = make_float2(0.5f * (c.y + d.y), 0.5f * (d.x - c.x));
    }
  }
}

// Column FFT * K_H (optionally conj) * column IFFT on the half-spectrum.
// grid = (513, ceil(zn/ZB)). kc in [1,511]: complex column kc. kc==0 / kc==512:
// the two real columns packed in stored col 0 (.x / .y). K column held in 8 VGPRs.
// in: [z][512][inLen]; out: [z][512][1024] (col 0 packs the two real results).
__global__ __launch_bounds__(256) void pass2_kernel(const cf* __restrict__ in, int inLen, int inOff,
                                                    const cf* __restrict__ kt, cf* __restrict__ out,
                                                    int zn, int ZB, int conjK) {
  __shared__ cf X[1088], Y[1088], TW[256];
  int tid = threadIdx.x;
  int kc = blockIdx.x;               // 0..512
  twinit(TW);
  const cf* krow = kt + (size_t)kc * NXY;
  cf kv[4];
#pragma unroll
  for (int j = 0; j < 4; ++j) {
    kv[j] = krow[tid + 256 * j];
    if (conjK) kv[j].y = -kv[j].y;
  }
  int srccol = (kc == 512) ? 0 : kc;
  int zlo = blockIdx.y * ZB, zhi = min(zn, zlo + ZB);
  for (int z = zlo; z < zhi; ++z) {
    const cf* src = in + ((size_t)z * 512 + srccol) * inLen;
    if (kc == 0 || kc == 512) {
      for (int k = tid; k < 1024; k += 256) {
        float v = 0.f;
        if (k >= inOff && k < inOff + inLen) {
          cf s = src[k - inOff];
          v = (kc == 0) ? s.x : s.y;
        }
        X[PAD(k)] = make_float2(v, 0.f);
      }
    } else {
      for (int k = tid; k < 1024; k += 256) {
        cf v = make_float2(0.f, 0.f);
        if (k >= inOff && k < inOff + inLen) v = src[k - inOff];
        X[PAD(k)] = v;
      }
    }
    cf* F = fft1024_r4<-1>(X, Y, TW);   // F == Y
#pragma unroll
    for (int j = 0; j < 4; ++j) {
      int p = PAD(tid + 256 * j);
      F[p] = cmul(F[p], kv[j]);
    }
    cf* G = fft1024_r4<1>(F, X, TW);    // G == X
    cf* dstz = out + (size_t)z * 512 * NXY;
    if (kc == 0) {
      for (int k = tid; k < 1024; k += 256) dstz[k].x = G[PAD(k)].x;
    } else if (kc == 512) {
      for (int k = tid; k < 1024; k += 256) dstz[k].y = G[PAD(k)].x;
    } else {
      for (int k = tid; k < 1024; k += 256) dstz[(size_t)kc * NXY + k] = G[PAD(k)];
    }
    __syncthreads();
  }
}

// Row irFFT (pair) + scale + ReLU, accumulate into partial plane a. grid = (512, NACC).
// in: [z][1024][512] (col 0 packed). Each block owns rows (2b, 2b+1).
__global__ __launch_bounds__(256) void pass3_fwd_kernel(const cf* __restrict__ in,
                                                        float* __restrict__ partials,
                                                        const float* __restrict__ ksump, int zn) {
  __shared__ cf X[1088], Y[1088], TW[256];
  int tid = threadIdx.x;
  int b = blockIdx.x, a = blockIdx.y;
  twinit(TW);
  float scale = 1.0f / (1048576.0f * ksump[0]);
  int r0 = 2 * b, r1 = 2 * b + 1;
  float acc[8] = {0.f, 0.f, 0.f, 0.f, 0.f, 0.f, 0.f, 0.f};
  for (int z = a; z < zn; z += NACC) {
    const cf* s0 = in + ((size_t)z * NXY + r0) * 512;
    const cf* s1 = s0 + 512;
    for (int k = tid; k < 512; k += 256) {
      cf u0 = s0[k], u1 = s1[k];
      if (k == 0) {
        X[PAD(0)]   = make_float2(u0.x, u1.x);
        X[PAD(512)] = make_float2(u0.y, u1.y);
      } else {
        X[PAD(k)]        = make_float2(u0.x - u1.y, u0.y + u1.x);
        X[PAD(1024 - k)] = make_float2(u0.x + u1.y, u1.x - u0.y);
      }
    }
    cf* G = fft1024_r4<1>(X, Y, TW);    // G == Y
#pragma unroll
    for (int j = 0; j < 4; ++j) {
      cf g = G[PAD(tid + 256 * j)];
      float v0 = g.x * scale, v1 = g.y * scale;
      acc[j]     += v0 > 0.f ? v0 : 0.f;
      acc[4 + j] += v1 > 0.f ? v1 : 0.f;
    }
    __syncthreads();
  }
  float* d0 = partials + ((size_t)a * NXY + r0) * NXY;
  float* d1 = d0 + NXY;
#pragma unroll
  for (int j = 0; j < 4; ++j) {
    d0[tid + 256 * j] += acc[j];
    d1[tid + 256 * j] += acc[4 + j];
  }
}

__global__ void fold_kernel(const float* __restrict__ partials, float* __restrict__ iest) {
  int i = blockIdx.x * 256 + threadIdx.x;
  float s = 0.f;
#pragma unroll
  for (int a = 0; a < NACC; ++a) s += partials[(size_t)a * NXY * NXY + i];
  iest[i] = s;
}

// Back-projection row irFFT (pair) + ReLU + multiply into obj. grid = (256): rows 256+2b, 257+2b.
__global__ __launch_bounds__(256) void pass3_back_kernel(const cf* __restrict__ in, float* __restrict__ obj,
                                                         const float* __restrict__ ksump) {
  __shared__ cf X[1088], Y[1088], TW[256];
  __shared__ float br0[512], br1[512];
  int tid = threadIdx.x, b = blockIdx.x;
  twinit(TW);
  float scale = 1.0f / (1048576.0f * ksump[0]);
  int r0 = LO_ + 2 * b, r1 = r0 + 1;
  const cf* s0 = in + (size_t)r0 * 512;
  const cf* s1 = in + (size_t)r1 * 512;
  for (int k = tid; k < 512; k += 256) {
    cf u0 = s0[k], u1 = s1[k];
    if (k == 0) {
      X[PAD(0)]   = make_float2(u0.x, u1.x);
      X[PAD(512)] = make_float2(u0.y, u1.y);
    } else {
      X[PAD(k)]        = make_float2(u0.x - u1.y, u0.y + u1.x);
      X[PAD(1024 - k)] = make_float2(u0.x + u1.y, u1.x - u0.y);
    }
  }
  cf* G = fft1024_r4<1>(X, Y, TW);
  for (int k = tid; k < 512; k += 256) {
    cf g = G[PAD(k + LO_)];
    float v0 = g.x * scale, v1 = g.y * scale;
    br0[k] = v0 > 0.f ? v0 : 0.f;
    br1[k] = v1 > 0.f ? v1 : 0.f;
  }
  __syncthreads();
  int rp0 = 2 * b, rp1 = 2 * b + 1;
  for (int idx = tid; idx < NZ * 512; idx += 256) {
    int z = idx >> 9, c = idx & 511;
    obj[((size_t)z * ROI2 + rp0) * ROI2 + c] *= br0[c];
    obj[((size_t)z * ROI2 + rp1) * ROI2 + c] *= br1[c];
  }
}

// ---------------- median (exact, 3-round radix-select: 11/11/10 bits) ----------------
__global__ void medinit_kernel(unsigned* st) {
  if (threadIdx.x == 0) { st[0] = 0u; st[1] = 0u; st[2] = RANK1; st[3] = RANK2; }
}

__global__ void medhist_kernel(const float* __restrict__ v, const unsigned* __restrict__ st,
                               unsigned* __restrict__ hist, int shift, unsigned maskHigh, int nb) {
  extern __shared__ unsigned h[];  // 2*nb
  int tid = threadIdx.x;
  for (int k = tid; k < 2 * nb; k += 256) h[k] = 0u;
  __syncthreads();
  unsigned p1 = st[0], p2 = st[1];
  unsigned bm = (unsigned)(nb - 1);
  for (int i = blockIdx.x * 256 + tid; i < NXY * NXY; i += gridDim.x * 256) {
    unsigned u = __float_as_uint(v[i]);
    unsigned b = (u >> shift) & bm;
    if ((u & maskHigh) == (p1 & maskHigh)) atomicAdd(&h[b], 1u);
    if ((u & maskHigh) == (p2 & maskHigh)) atomicAdd(&h[nb + b], 1u);
  }
  __syncthreads();
  for (int k = tid; k < 2 * nb; k += 256) atomicAdd(&hist[k], h[k]);
}

__global__ void medpick_kernel(unsigned* st, const unsigned* __restrict__ hist, int shift, int nb,
                               int finalRound, float* tos) {
  __shared__ unsigned ps[256];
  int t = threadIdx.x;
  int per = nb >> 8;  // nb/256 (<= 8)
  for (int which = 0; which < 2; ++which) {
    unsigned loc[8];
    unsigned my = 0;
    for (int i = 0; i < per; ++i) { loc[i] = hist[which * nb + t * per + i]; my += loc[i]; }
    ps[t] = my;
    __syncthreads();
    for (int off = 1; off < 256; off <<= 1) {
      unsigned v = (t >= off) ? ps[t - off] : 0u;
      __syncthreads();
      ps[t] += v;
      __syncthreads();
    }
    unsigned pre = ps[t] - my;
    unsigned r = st[2 + which];
    if (r >= pre && r < pre + my) {
      unsigned cum = pre;
      for (int i = 0; i < per; ++i) {
        if (r < cum + loc[i]) {
          st[which] |= (unsigned)(t * per + i) << shift;
          st[2 + which] = r - cum;
          break;
        }
        cum += loc[i];
      }
    }
    __syncthreads();
  }
  if (finalRound && t == 0) {
    float m = 0.5f * (__uint_as_float(st[0]) + __uint_as_float(st[1]));
    tos[0] = m / SNR_;
  }
}

// ---------------- orchestration ----------------
extern "C" void kernel_launch(void* const* d_in, const int* in_sizes, int n_in,
                              void* d_out, int out_size, void* d_ws, size_t ws_size,
                              hipStream_t stream) {
  const float* imstack  = (const float*)d_in[0];
  const float* init_vol = (const float*)d_in[1];
  const float* conv_re  = (const float*)d_in[2];
  const float* conv_im  = (const float*)d_in[3];
  float* obj = (float*)d_out;

  char* w = (char*)d_ws;
  size_t off = 0;
  auto alloc = [&](size_t bytes) -> void* {
    void* p = (void*)(w + off);
    off += (bytes + 255) & ~(size_t)255;
    return p;
  };

  const size_t PLANE = (size_t)NXY * NXY;
  const size_t HPLANE = (size_t)512 * NXY;                    // half-spectrum plane (cf)
  cf* KT         = (cf*)alloc((size_t)513 * NXY * sizeof(cf)); // 4.2 MB (K_H, transposed)
  float* IExp    = (float*)alloc(PLANE * 4);                   // 4 MB
  float* IEst    = (float*)alloc(PLANE * 4);                   // 4 MB
  float* Partial = (float*)alloc((size_t)NACC * PLANE * 4);    // 32 MB
  float* Ksum    = (float*)alloc(256);
  unsigned* St   = (unsigned*)alloc(256);
  unsigned* Hist = (unsigned*)alloc(2 * 2048 * 4);
  size_t fixedEnd = off;

  int ZC = 1;
  const int zcs[8] = {24, 12, 8, 6, 4, 3, 2, 1};
  for (int i = 0; i < 8; ++i) {
    size_t need = fixedEnd + (size_t)zcs[i] * 2ull * HPLANE * sizeof(cf) + 4096;
    if (need <= ws_size) { ZC = zcs[i]; break; }
  }
  cf* bufC = (cf*)alloc((size_t)ZC * HPLANE * sizeof(cf));     // 4 MB/slice
  cf* bufD = (cf*)alloc((size_t)ZC * HPLANE * sizeof(cf));
  float* Tos = Ksum + 1;

  hipMemcpyAsync(obj, init_vol, (size_t)NZ * ROI2 * ROI2 * 4, hipMemcpyDeviceToDevice, stream);
  hipMemsetAsync(Ksum, 0, 8, stream);
  ksum_kernel<<<256, 256, 0, stream>>>(conv_re, Ksum);
  imgexp_kernel<<<4096, 256, 0, stream>>>(imstack, IExp);
  buildkh_kernel<<<2052, 256, 0, stream>>>(conv_re, conv_im, KT);

  const int shifts[3] = {21, 10, 0};
  const int nbs[3]    = {2048, 2048, 1024};
  const unsigned masks[3] = {0u, 0xFFE00000u, 0xFFFFFC00u};

  for (int it = 0; it < ITN; ++it) {
    hipMemsetAsync(Partial, 0, (size_t)NACC * PLANE * 4, stream);
    // forward projection in z-chunks (half-spectrum pipeline)
    for (int z0 = 0; z0 < NZ; z0 += ZC) {
      int zn = (NZ - z0 < ZC) ? (NZ - z0) : ZC;
      int nzb = (zn + 3) / 4;
      // rows: 512 real rows/slice -> 256 pair-FFTs; out [z][512][512]
      pass1_kernel<<<dim3(256, zn), 256, 0, stream>>>(obj + (size_t)z0 * ROI2 * ROI2, ROI2, LO_, bufC);
      // [z][512r][512kx] -> [z][512kx][512r]
      transpose_kernel<<<dim3(16, 16, zn), dim3(32, 8), 0, stream>>>(bufC, bufD, 512, 512);
      // columns: 513 (2 packed-real) -> out [z][512][1024]
      pass2_kernel<<<dim3(513, nzb), 256, 0, stream>>>(bufD, 512, LO_, KT, bufC, zn, 4, 0);
      // [z][512kx][1024y] -> [z][1024y][512kx]
      transpose_kernel<<<dim3(32, 16, zn), dim3(32, 8), 0, stream>>>(bufC, bufD, 512, 1024);
      // rows back: 512 pair-irFFTs/slice, accumulate
      pass3_fwd_kernel<<<dim3(512, NACC), 256, 0, stream>>>(bufD, Partial, Ksum, zn);
    }
    fold_kernel<<<4096, 256, 0, stream>>>(Partial, IEst);
    // exact median of IEst
    medinit_kernel<<<1, 64, 0, stream>>>(St);
    for (int round = 0; round < 3; ++round) {
      hipMemsetAsync(Hist, 0, 2 * 2048 * 4, stream);
      medhist_kernel<<<256, 256, 2 * nbs[round] * 4, stream>>>(IEst, St, Hist, shifts[round],
                                                               masks[round], nbs[round]);
      medpick_kernel<<<1, 256, 0, stream>>>(St, Hist, shifts[round], nbs[round],
                                            round == 2 ? 1 : 0, Tos);
    }
    // back projection (ratio fused; conj(K_H))
    pass1b_kernel<<<512, 256, 0, stream>>>(IExp, IEst, Tos, bufC);          // [1024][512]
    transpose_kernel<<<dim3(16, 32, 1), dim3(32, 8), 0, stream>>>(bufC, bufD, 1024, 512);
    pass2_kernel<<<dim3(513, 1), 256, 0, stream>>>(bufD, 1024, 0, KT, bufC, 1, 1, 1);
    transpose_kernel<<<dim3(32, 16, 1), dim3(32, 8), 0, stream>>>(bufC, bufD, 512, 1024);
    pass3_back_kernel<<<256, 256, 0, stream>>>(bufD, obj, Ksum);
  }
}

// Round 6
// 632.775 us; speedup vs baseline: 2.3619x; 1.1155x over previous
//
#include <hip/hip_runtime.h>
#include <math.h>

#define NXY  1024
#define NZ   24
#define ROI2 512      // 2*ROISize
#define LO_  256      // Nxy/2 - ROISize
#define EXT  64       // NxyExt
#define IMGW 896      // Nxy - 2*EXT
#define ITN  2
#define SNR_ 200.0f
#define BKG  110.0f
#define RANK1 524287u
#define RANK2 524288u
#define NACC 4
// Bijective LDS swizzle; with the per-stage twiddle tables below, every Stockham
// read/write pattern is at the b64 bank minimum (verified per-stage on paper).
#define SWZ(i) ((i) ^ ((((i) >> 4) & 3) * 5))

typedef float2 cf;

__device__ __forceinline__ cf cadd(cf a, cf b) { return make_float2(a.x + b.x, a.y + b.y); }
__device__ __forceinline__ cf csub(cf a, cf b) { return make_float2(a.x - b.x, a.y - b.y); }
__device__ __forceinline__ cf cmul(cf a, cf b) { return make_float2(a.x * b.x - a.y * b.y, a.x * b.y + a.y * b.x); }

struct Tw { const cf *t0, *t1, *t2, *t3; };

// Per-stage forward twiddle tables: TW0[k]=W^k (k<256), T1[k]=W^{4k} (k<64),
// T2[k]=W^{16k} (k<16), T3[k]=W^{64k} (k<4). Stage-t lookups are contiguous or
// broadcast -> no bank conflicts (the single shared table had 4-way at stages 1-2).
__device__ __forceinline__ void twinit_all(cf* TW0, cf* T1, cf* T2, cf* T3) {
  const float W = -6.28318530717958647692f / 1024.0f;
  int k = threadIdx.x;
  float s, c;
  sincosf(W * (float)k, &s, &c);
  TW0[k] = make_float2(c, s);
  if (k < 64) { sincosf(W * (float)(4 * k), &s, &c);  T1[k] = make_float2(c, s); }
  if (k < 16) { sincosf(W * (float)(16 * k), &s, &c); T2[k] = make_float2(c, s); }
  if (k < 4)  { sincosf(W * (float)(64 * k), &s, &c); T3[k] = make_float2(c, s); }
}

// Radix-4 Stockham DIF stages [T0,5). Call with the buffer stage T0 reads as src.
// SIGN=-1 fwd, +1 inverse (unnormalized). Result buffer returned (natural order).
template <int SIGN, int T0>
__device__ cf* fft1024_r4_t(cf* src, cf* dst, Tw tw) {
  const int tid = threadIdx.x;
#pragma unroll
  for (int t = T0; t < 5; ++t) {
    __syncthreads();
    const int s = 1 << (2 * t);
    const int q = tid & (s - 1);
    cf a0 = src[SWZ(tid)];
    cf a1 = src[SWZ(tid + 256)];
    cf a2 = src[SWZ(tid + 512)];
    cf a3 = src[SWZ(tid + 768)];
    cf b0 = cadd(a0, a2), b1 = csub(a0, a2);
    cf b2 = cadd(a1, a3), b3 = csub(a1, a3);
    cf jb3 = (SIGN < 0) ? make_float2(b3.y, -b3.x) : make_float2(-b3.y, b3.x);
    cf c0 = cadd(b0, b2);
    cf c2 = csub(b0, b2);
    cf c1 = cadd(b1, jb3);
    cf c3 = csub(b1, jb3);
    const int base = 4 * tid - 3 * q;  // q + s*4p
    if (t == 4) {                      // last stage: twiddles are all 1
      dst[SWZ(base)]         = c0;
      dst[SWZ(base + s)]     = c1;
      dst[SWZ(base + 2 * s)] = c2;
      dst[SWZ(base + 3 * s)] = c3;
    } else {
      cf t1v = (t == 0) ? tw.t0[tid] : (t == 1) ? tw.t1[tid >> 2]
             : (t == 2) ? tw.t2[tid >> 4] : tw.t3[tid >> 6];
      if (SIGN > 0) t1v.y = -t1v.y;
      cf t2v = cmul(t1v, t1v);
      cf t3v = cmul(t2v, t1v);
      dst[SWZ(base)]         = c0;
      dst[SWZ(base + s)]     = cmul(c1, t1v);
      dst[SWZ(base + 2 * s)] = cmul(c2, t2v);
      dst[SWZ(base + 3 * s)] = cmul(c3, t3v);
    }
    cf* tmp = src; src = dst; dst = tmp;
  }
  __syncthreads();
  return src;
}

// Forward stage-0 specialized for inputs nonzero only at k in [256,768):
// a1 = x[256+tid], a2 = x[512+tid]; a0 = a3 = 0. Writes stage-0 output to dst.
__device__ __forceinline__ void fft_stage0_half(cf a1, cf a2, cf* dst, const cf* TW0) {
  const int tid = threadIdx.x;
  cf b1 = make_float2(-a2.x, -a2.y);        // b0 = a2, b2 = b3 = a1
  cf jb3 = make_float2(a1.y, -a1.x);        // fwd: -i*a1
  cf c0 = cadd(a2, a1);
  cf c2 = csub(a2, a1);
  cf c1 = cadd(b1, jb3);
  cf c3 = csub(b1, jb3);
  cf t1v = TW0[tid];
  cf t2v = cmul(t1v, t1v);
  cf t3v = cmul(t2v, t1v);
  const int base = 4 * tid;
  dst[SWZ(base)]     = c0;
  dst[SWZ(base + 1)] = cmul(c1, t1v);
  dst[SWZ(base + 2)] = cmul(c2, t2v);
  dst[SWZ(base + 3)] = cmul(c3, t3v);
}

// ---------------- setup kernels ----------------
__global__ void ksum_kernel(const float* __restrict__ a, float* __restrict__ out) {
  __shared__ float s[256];
  int tid = threadIdx.x;
  float acc = 0.f;
  for (int i = blockIdx.x * 256 + tid; i < NXY * NXY; i += gridDim.x * 256) acc += a[i];
  s[tid] = acc;
  __syncthreads();
  for (int o = 128; o > 0; o >>= 1) {
    if (tid < o) s[tid] += s[tid + o];
    __syncthreads();
  }
  if (tid == 0) atomicAdd(out, s[0]);
}

__global__ void imgexp_kernel(const float* __restrict__ im, float* __restrict__ out) {
  int idx = blockIdx.x * 256 + threadIdx.x;
  int r = idx >> 10, c = idx & 1023;
  float v = 0.f;
  if (r >= EXT && r < NXY - EXT && c >= EXT && c < NXY - EXT) {
    float t = im[(size_t)(r - EXT) * IMGW + (c - EXT)] - BKG;
    v = t > 0.f ? t : 0.f;
  }
  out[idx] = v;
}

// KH_T[kx][ky] = Hermitian part of K, transposed. Re(ifft2(F*K)) == ifft2(F*K_H).
__global__ void buildkh_kernel(const float* __restrict__ kre, const float* __restrict__ kim,
                               cf* __restrict__ kt) {
  int idx = blockIdx.x * 256 + threadIdx.x;
  if (idx >= 513 * 1024) return;
  int ky = idx & 1023, kx = idx >> 10;
  int ny = (1024 - ky) & 1023, nx = (1024 - kx) & 1023;
  float ar = kre[(size_t)ky * NXY + kx], ai = kim[(size_t)ky * NXY + kx];
  float br = kre[(size_t)ny * NXY + nx], bi = kim[(size_t)ny * NXY + nx];
  kt[idx] = make_float2(0.5f * (ar + br), 0.5f * (ai - bi));
}

// transpose [R][C] -> [C][R], batched over blockIdx.z; grid (C/32, R/32, z)
__global__ void transpose_kernel(const cf* __restrict__ in, cf* __restrict__ out, int R, int C) {
  __shared__ cf tile[32][33];
  size_t zoff = (size_t)blockIdx.z * R * C;
  const cf* src = in + zoff;
  cf* dst = out + zoff;
  int bc = blockIdx.x * 32, br = blockIdx.y * 32;
  int tx = threadIdx.x, ty = threadIdx.y;
#pragma unroll
  for (int j = 0; j < 32; j += 8) tile[ty + j][tx] = src[(size_t)(br + ty + j) * C + bc + tx];
  __syncthreads();
#pragma unroll
  for (int j = 0; j < 32; j += 8) dst[(size_t)(bc + ty + j) * R + br + tx] = tile[tx][ty + j];
}

// ---------------- FFT pipeline kernels ----------------
// Row rFFT of TWO real 512-long rows (ROI), stage-0 folded into the load.
// grid = (256, zn). in: [z][512][512] f32; out: [z][512][512] cf half-spectra
// (col 0 packs (F[0], F[512]), both real).
__global__ __launch_bounds__(256) void pass1_kernel(const float* __restrict__ in, cf* __restrict__ out) {
  __shared__ cf X[1024], Y[1024], TW0[256], T1[64], T2[16], T3[4];
  int tid = threadIdx.x, b = blockIdx.x, zl = blockIdx.y;
  twinit_all(TW0, T1, T2, T3);
  const float* r0 = in + ((size_t)zl * 512 + 2 * b) * 512;
  const float* r1 = r0 + 512;
  cf a1 = make_float2(r0[tid], r1[tid]);              // k = 256+tid
  cf a2 = make_float2(r0[tid + 256], r1[tid + 256]);  // k = 512+tid
  fft_stage0_half(a1, a2, Y, TW0);
  Tw tw{TW0, T1, T2, T3};
  cf* G = fft1024_r4_t<-1, 1>(Y, X, tw);
  cf* o0 = out + ((size_t)zl * 512 + 2 * b) * 512;
  cf* o1 = o0 + 512;
  for (int k = tid; k < 512; k += 256) {
    if (k == 0) {
      cf g0 = G[SWZ(0)], gn = G[SWZ(512)];
      o0[0] = make_float2(g0.x, gn.x);
      o1[0] = make_float2(g0.y, gn.y);
    } else {
      cf c = G[SWZ(k)], d = G[SWZ(1024 - k)];
      o0[k] = make_float2(0.5f * (c.x + d.x), 0.5f * (c.y - d.y));
      o1[k] = make_float2(0.5f * (c.y + d.y), 0.5f * (d.x - c.x));
    }
  }
}

// Back-projection row rFFT with ratio fused. grid = (512). rows (2b,2b+1); out [1024][512].
__global__ __launch_bounds__(256) void pass1b_kernel(const float* __restrict__ iexp,
                                                     const float* __restrict__ iest,
                                                     const float* __restrict__ tos,
                                                     cf* __restrict__ out) {
  __shared__ cf X[1024], Y[1024], TW0[256], T1[64], T2[16], T3[4];
  int tid = threadIdx.x, b = blockIdx.x;
  twinit_all(TW0, T1, T2, T3);
  float t = tos[0];
  int r0 = 2 * b, r1 = 2 * b + 1;
  bool in0 = (r0 >= EXT && r0 < NXY - EXT);
  bool in1 = (r1 >= EXT && r1 < NXY - EXT);
  for (int k = tid; k < 1024; k += 256) {
    bool kin = (k >= EXT && k < NXY - EXT);
    float v0 = (in0 && kin) ? iexp[(size_t)r0 * NXY + k] / (iest[(size_t)r0 * NXY + k] + t) : 1.0f;
    float v1 = (in1 && kin) ? iexp[(size_t)r1 * NXY + k] / (iest[(size_t)r1 * NXY + k] + t) : 1.0f;
    X[SWZ(k)] = make_float2(v0, v1);
  }
  Tw tw{TW0, T1, T2, T3};
  cf* G = fft1024_r4_t<-1, 0>(X, Y, tw);
  cf* o0 = out + (size_t)r0 * 512;
  cf* o1 = out + (size_t)r1 * 512;
  for (int k = tid; k < 512; k += 256) {
    if (k == 0) {
      cf g0 = G[SWZ(0)], gn = G[SWZ(512)];
      o0[0] = make_float2(g0.x, gn.x);
      o1[0] = make_float2(g0.y, gn.y);
    } else {
      cf c = G[SWZ(k)], d = G[SWZ(1024 - k)];
      o0[k] = make_float2(0.5f * (c.x + d.x), 0.5f * (c.y - d.y));
      o1[k] = make_float2(0.5f * (c.y + d.y), 0.5f * (d.x - c.x));
    }
  }
}

// Column FFT * K_H (optionally conj) * column IFFT on the half-spectrum.
// grid = (512, ceil(zn/ZB)). Block kc==0 handles BOTH packed real columns
// (kx=0 and kx=512) via the two-real-FFT split. HALFIN=1: input columns have
// nonzero support [256,768) (forward path) -> stage-0 folded into load.
// in: [z][512][inLen] cf; out: [z][512][NXY] cf (row 0 = packed real results).
template <int HALFIN>
__global__ __launch_bounds__(256) void pass2_kernel(const cf* __restrict__ in,
                                                    const cf* __restrict__ kt, cf* __restrict__ out,
                                                    int zn, int ZB, int conjK) {
  __shared__ cf X[1024], Y[1024], TW0[256], T1[64], T2[16], T3[4];
  int tid = threadIdx.x, kc = blockIdx.x;
  twinit_all(TW0, T1, T2, T3);
  Tw tw{TW0, T1, T2, T3};
  cf kva[4], kvb[4];
#pragma unroll
  for (int j = 0; j < 4; ++j) {
    kva[j] = kt[(size_t)kc * NXY + tid + 256 * j];
    if (conjK) kva[j].y = -kva[j].y;
  }
  if (kc == 0) {
#pragma unroll
    for (int j = 0; j < 4; ++j) {
      kvb[j] = kt[(size_t)512 * NXY + tid + 256 * j];
      if (conjK) kvb[j].y = -kvb[j].y;
    }
  }
  const int inLen = HALFIN ? 512 : 1024;
  int zlo = blockIdx.y * ZB, zhi = min(zn, zlo + ZB);
  for (int z = zlo; z < zhi; ++z) {
    const cf* src = in + ((size_t)z * 512 + kc) * inLen;
    cf* F;
    if (HALFIN) {
      cf a1 = src[tid], a2 = src[tid + 256];
      fft_stage0_half(a1, a2, Y, TW0);
      F = fft1024_r4_t<-1, 1>(Y, X, tw);     // returns Y
    } else {
      for (int k = tid; k < 1024; k += 256) X[SWZ(k)] = src[k];
      F = fft1024_r4_t<-1, 0>(X, Y, tw);     // returns Y
    }
    if (kc == 0) {
      cf fk[4], fn[4];
#pragma unroll
      for (int j = 0; j < 4; ++j) {
        int k = tid + 256 * j, nk = (1024 - k) & 1023;
        fk[j] = F[SWZ(k)];
        fn[j] = F[SWZ(nk)];
      }
      __syncthreads();
#pragma unroll
      for (int j = 0; j < 4; ++j) {
        int k = tid + 256 * j;
        cf Fa = make_float2(0.5f * (fk[j].x + fn[j].x), 0.5f * (fk[j].y - fn[j].y));
        cf Fb = make_float2(0.5f * (fk[j].y + fn[j].y), 0.5f * (fn[j].x - fk[j].x));
        cf Ga = cmul(Fa, kva[j]);
        cf Gb = cmul(Fb, kvb[j]);
        F[SWZ(k)] = make_float2(Ga.x - Gb.y, Ga.y + Gb.x);
      }
    } else {
#pragma unroll
      for (int j = 0; j < 4; ++j) {
        int p = SWZ(tid + 256 * j);
        F[p] = cmul(F[p], kva[j]);
      }
    }
    cf* G = fft1024_r4_t<1, 0>(F, (F == X) ? Y : X, tw);  // returns X
    cf* dst = out + ((size_t)z * 512 + kc) * NXY;
    for (int k = tid; k < 1024; k += 256) dst[k] = G[SWZ(k)];
  }
}

// Row irFFT (pair) + scale + ReLU into partial plane a. grid = (512, NACC).
// in: [z][1024][512] cf (col 0 packed). Block owns rows (2b, 2b+1).
__global__ __launch_bounds__(256) void pass3_fwd_kernel(const cf* __restrict__ in,
                                                        float* __restrict__ partials,
                                                        const float* __restrict__ ksump, int zn,
                                                        int accum) {
  __shared__ cf X[1024], Y[1024], TW0[256], T1[64], T2[16], T3[4];
  int tid = threadIdx.x, b = blockIdx.x, a = blockIdx.y;
  twinit_all(TW0, T1, T2, T3);
  Tw tw{TW0, T1, T2, T3};
  float scale = 1.0f / (1048576.0f * ksump[0]);
  int r0 = 2 * b, r1 = 2 * b + 1;
  float acc[8] = {0.f, 0.f, 0.f, 0.f, 0.f, 0.f, 0.f, 0.f};
  for (int z = a; z < zn; z += NACC) {
    const cf* s0 = in + ((size_t)z * NXY + r0) * 512;
    const cf* s1 = s0 + 512;
    for (int k = tid; k < 512; k += 256) {
      cf u0 = s0[k], u1 = s1[k];
      if (k == 0) {
        X[SWZ(0)]   = make_float2(u0.x, u1.x);
        X[SWZ(512)] = make_float2(u0.y, u1.y);
      } else {
        X[SWZ(k)]        = make_float2(u0.x - u1.y, u0.y + u1.x);
        X[SWZ(1024 - k)] = make_float2(u0.x + u1.y, u1.x - u0.y);
      }
    }
    cf* G = fft1024_r4_t<1, 0>(X, Y, tw);   // returns Y; trailing barrier in fft
#pragma unroll
    for (int j = 0; j < 4; ++j) {
      cf g = G[SWZ(tid + 256 * j)];
      float v0 = g.x * scale, v1 = g.y * scale;
      acc[j]     += v0 > 0.f ? v0 : 0.f;
      acc[4 + j] += v1 > 0.f ? v1 : 0.f;
    }
    // no barrier needed: next X-fill writes X; last X reads (stage 4) are behind
    // the fft's trailing barrier, and acc reads Y (own slots).
  }
  float* d0 = partials + ((size_t)a * NXY + r0) * NXY;
  float* d1 = d0 + NXY;
  if (accum) {
#pragma unroll
    for (int j = 0; j < 4; ++j) { d0[tid + 256 * j] += acc[j]; d1[tid + 256 * j] += acc[4 + j]; }
  } else {
#pragma unroll
    for (int j = 0; j < 4; ++j) { d0[tid + 256 * j] = acc[j]; d1[tid + 256 * j] = acc[4 + j]; }
  }
}

// fold partials -> IEst; re-init median state
__global__ void fold_kernel(const float* __restrict__ partials, float* __restrict__ iest,
                            unsigned* __restrict__ st) {
  int i = blockIdx.x * 256 + threadIdx.x;
  float s = 0.f;
#pragma unroll
  for (int a = 0; a < NACC; ++a) s += partials[(size_t)a * NXY * NXY + i];
  iest[i] = s;
  if (i == 0) { st[0] = 0u; st[1] = 0u; st[2] = RANK1; st[3] = RANK2; }
}

// Back-projection row irFFT (pair) + ReLU + multiply into obj. grid = (256).
__global__ __launch_bounds__(256) void pass3_back_kernel(const cf* __restrict__ in, float* __restrict__ obj,
                                                         const float* __restrict__ ksump) {
  __shared__ cf X[1024], Y[1024], TW0[256], T1[64], T2[16], T3[4];
  __shared__ float br0[512], br1[512];
  int tid = threadIdx.x, b = blockIdx.x;
  twinit_all(TW0, T1, T2, T3);
  Tw tw{TW0, T1, T2, T3};
  float scale = 1.0f / (1048576.0f * ksump[0]);
  int r0 = LO_ + 2 * b, r1 = r0 + 1;
  const cf* s0 = in + (size_t)r0 * 512;
  const cf* s1 = in + (size_t)r1 * 512;
  for (int k = tid; k < 512; k += 256) {
    cf u0 = s0[k], u1 = s1[k];
    if (k == 0) {
      X[SWZ(0)]   = make_float2(u0.x, u1.x);
      X[SWZ(512)] = make_float2(u0.y, u1.y);
    } else {
      X[SWZ(k)]        = make_float2(u0.x - u1.y, u0.y + u1.x);
      X[SWZ(1024 - k)] = make_float2(u0.x + u1.y, u1.x - u0.y);
    }
  }
  cf* G = fft1024_r4_t<1, 0>(X, Y, tw);
  for (int k = tid; k < 512; k += 256) {
    cf g = G[SWZ(k + LO_)];
    float v0 = g.x * scale, v1 = g.y * scale;
    br0[k] = v0 > 0.f ? v0 : 0.f;
    br1[k] = v1 > 0.f ? v1 : 0.f;
  }
  __syncthreads();
  int rp0 = 2 * b, rp1 = 2 * b + 1;
  for (int idx = tid; idx < NZ * 512; idx += 256) {
    int z = idx >> 9, c = idx & 511;
    obj[((size_t)z * ROI2 + rp0) * ROI2 + c] *= br0[c];
    obj[((size_t)z * ROI2 + rp1) * ROI2 + c] *= br1[c];
  }
}

// ---------------- median (exact, 3-round radix-select: 11/11/10 bits) ----------------
__global__ void medhist_kernel(const float* __restrict__ v, const unsigned* __restrict__ st,
                               unsigned* __restrict__ hist, int shift, unsigned maskHigh, int nb) {
  extern __shared__ unsigned h[];
  int tid = threadIdx.x;
  for (int k = tid; k < 2 * nb; k += 256) h[k] = 0u;
  __syncthreads();
  unsigned p1 = st[0], p2 = st[1];
  unsigned bm = (unsigned)(nb - 1);
  for (int i = blockIdx.x * 256 + tid; i < NXY * NXY; i += gridDim.x * 256) {
    unsigned u = __float_as_uint(v[i]);
    unsigned b = (u >> shift) & bm;
    if ((u & maskHigh) == (p1 & maskHigh)) atomicAdd(&h[b], 1u);
    if ((u & maskHigh) == (p2 & maskHigh)) atomicAdd(&h[nb + b], 1u);
  }
  __syncthreads();
  for (int k = tid; k < 2 * nb; k += 256) atomicAdd(&hist[k], h[k]);
}

__global__ void medpick_kernel(unsigned* st, const unsigned* __restrict__ hist, int shift, int nb,
                               int finalRound, float* tos) {
  __shared__ unsigned ps[256];
  int t = threadIdx.x;
  int per = nb >> 8;
  for (int which = 0; which < 2; ++which) {
    unsigned loc[8];
    unsigned my = 0;
    for (int i = 0; i < per; ++i) { loc[i] = hist[which * nb + t * per + i]; my += loc[i]; }
    ps[t] = my;
    __syncthreads();
    for (int off = 1; off < 256; off <<= 1) {
      unsigned v = (t >= off) ? ps[t - off] : 0u;
      __syncthreads();
      ps[t] += v;
      __syncthreads();
    }
    unsigned pre = ps[t] - my;
    unsigned r = st[2 + which];
    if (r >= pre && r < pre + my) {
      unsigned cum = pre;
      for (int i = 0; i < per; ++i) {
        if (r < cum + loc[i]) {
          st[which] |= (unsigned)(t * per + i) << shift;
          st[2 + which] = r - cum;
          break;
        }
        cum += loc[i];
      }
    }
    __syncthreads();
  }
  if (finalRound && t == 0) {
    float m = 0.5f * (__uint_as_float(st[0]) + __uint_as_float(st[1]));
    tos[0] = m / SNR_;
  }
}

// ---------------- orchestration ----------------
extern "C" void kernel_launch(void* const* d_in, const int* in_sizes, int n_in,
                              void* d_out, int out_size, void* d_ws, size_t ws_size,
                              hipStream_t stream) {
  const float* imstack  = (const float*)d_in[0];
  const float* init_vol = (const float*)d_in[1];
  const float* conv_re  = (const float*)d_in[2];
  const float* conv_im  = (const float*)d_in[3];
  float* obj = (float*)d_out;

  char* w = (char*)d_ws;
  size_t off = 0;
  auto alloc = [&](size_t bytes) -> void* {
    void* p = (void*)(w + off);
    off += (bytes + 255) & ~(size_t)255;
    return p;
  };

  const size_t PLANE = (size_t)NXY * NXY;
  const size_t HPLANE = (size_t)512 * NXY;                     // half-spectrum elems/slice
  cf* KT         = (cf*)alloc((size_t)513 * NXY * sizeof(cf)); // 4.2 MB
  float* IExp    = (float*)alloc(PLANE * 4);                   // 4 MB
  float* IEst    = (float*)alloc(PLANE * 4);                   // 4 MB
  float* Partial = (float*)alloc((size_t)NACC * PLANE * 4);    // 16 MB
  float* Ksum    = (float*)alloc(256);
  unsigned* St   = (unsigned*)alloc(256);
  unsigned* Hist = (unsigned*)alloc(3 * 2 * 2048 * 4);
  size_t fixedEnd = off;

  int ZC = 2;
  const int zcs[7] = {24, 12, 8, 6, 4, 3, 2};
  for (int i = 0; i < 7; ++i) {
    size_t need = fixedEnd + (size_t)zcs[i] * 2ull * HPLANE * sizeof(cf) + 4096;
    if (need <= ws_size) { ZC = zcs[i]; break; }
  }
  cf* bufC = (cf*)alloc((size_t)ZC * HPLANE * sizeof(cf));     // 4 MB/slice
  cf* bufD = (cf*)alloc((size_t)ZC * HPLANE * sizeof(cf));
  float* Tos = Ksum + 1;

  hipMemcpyAsync(obj, init_vol, (size_t)NZ * ROI2 * ROI2 * 4, hipMemcpyDeviceToDevice, stream);
  hipMemsetAsync(Ksum, 0, 8, stream);
  ksum_kernel<<<256, 256, 0, stream>>>(conv_re, Ksum);
  imgexp_kernel<<<4096, 256, 0, stream>>>(imstack, IExp);
  buildkh_kernel<<<2052, 256, 0, stream>>>(conv_re, conv_im, KT);

  const int shifts[3] = {21, 10, 0};
  const int nbs[3]    = {2048, 2048, 1024};
  const unsigned masks[3] = {0u, 0xFFE00000u, 0xFFFFFC00u};

  for (int it = 0; it < ITN; ++it) {
    // forward projection in z-chunks (f32 half-spectrum pipeline)
    for (int z0 = 0; z0 < NZ; z0 += ZC) {
      int zn = (NZ - z0 < ZC) ? (NZ - z0) : ZC;
      int nzb = (zn + 5) / 6;
      pass1_kernel<<<dim3(256, zn), 256, 0, stream>>>(obj + (size_t)z0 * ROI2 * ROI2, bufC);
      transpose_kernel<<<dim3(16, 16, zn), dim3(32, 8), 0, stream>>>(bufC, bufD, 512, 512);
      pass2_kernel<1><<<dim3(512, nzb), 256, 0, stream>>>(bufD, KT, bufC, zn, 6, 0);
      transpose_kernel<<<dim3(32, 16, zn), dim3(32, 8), 0, stream>>>(bufC, bufD, 512, 1024);
      pass3_fwd_kernel<<<dim3(512, NACC), 256, 0, stream>>>(bufD, Partial, Ksum, zn, z0 > 0 ? 1 : 0);
    }
    fold_kernel<<<4096, 256, 0, stream>>>(Partial, IEst, St);
    // exact median of IEst
    hipMemsetAsync(Hist, 0, 3 * 2 * 2048 * 4, stream);
    for (int round = 0; round < 3; ++round) {
      medhist_kernel<<<256, 256, 2 * nbs[round] * 4, stream>>>(IEst, St, Hist + round * 4096,
                                                               shifts[round], masks[round], nbs[round]);
      medpick_kernel<<<1, 256, 0, stream>>>(St, Hist + round * 4096, shifts[round], nbs[round],
                                            round == 2 ? 1 : 0, Tos);
    }
    // back projection (ratio fused; conj(K_H); full-input path)
    pass1b_kernel<<<512, 256, 0, stream>>>(IExp, IEst, Tos, bufC);                   // [1024][512]
    transpose_kernel<<<dim3(16, 32, 1), dim3(32, 8), 0, stream>>>(bufC, bufD, 1024, 512);
    pass2_kernel<0><<<dim3(512, 1), 256, 0, stream>>>(bufD, KT, bufC, 1, 1, 1);      // [512][1024]
    transpose_kernel<<<dim3(32, 16, 1), dim3(32, 8), 0, stream>>>(bufC, bufD, 512, 1024);
    pass3_back_kernel<<<256, 256, 0, stream>>>(bufD, obj, Ksum);
  }
}